// Round 1
// baseline (96.932 us; speedup 1.0000x reference)
//
#include <hip/hip_runtime.h>
#include <math.h>

#define BN 16
#define DN 2048
#define ADA 1024
#define INTER 1024
#define NW2 32768   // D*RANK*2
#define HALFN 16384

// ---------------------------------------------------------------------------
// K1a: h_pre[m][j] += sum over k-chunk of ada[m][k]*w1[k][j]   (atomic k-split)
// grid: (jtiles=4, ksplit=32), block 256. kchunk = 32.
__global__ void k1a(const float* __restrict__ ada, const float* __restrict__ w1,
                    float* __restrict__ h_pre) {
    const int j  = blockIdx.x * 256 + threadIdx.x;
    const int k0 = blockIdx.y * 32;
    __shared__ float a_lds[BN][32];
    for (int idx = threadIdx.x; idx < BN * 32; idx += 256) {
        int m = idx >> 5, kk = idx & 31;
        a_lds[m][kk] = ada[m * ADA + k0 + kk];
    }
    __syncthreads();
    float acc[BN];
#pragma unroll
    for (int m = 0; m < BN; ++m) acc[m] = 0.f;
    for (int kk = 0; kk < 32; ++kk) {
        float w = w1[(k0 + kk) * INTER + j];
#pragma unroll
        for (int m = 0; m < BN; ++m) acc[m] += a_lds[m][kk] * w;
    }
#pragma unroll
    for (int m = 0; m < BN; ++m) atomicAdd(&h_pre[m * INTER + j], acc[m]);
}

// ---------------------------------------------------------------------------
// K1b: h = gelu_exact(h_pre + b1)   (16*1024 elements)
__global__ void k1b(const float* __restrict__ h_pre, const float* __restrict__ b1,
                    float* __restrict__ h) {
    int i = blockIdx.x * 256 + threadIdx.x;
    int j = i & (INTER - 1);
    float v = h_pre[i] + b1[j];
    h[i] = 0.5f * v * (1.f + erff(v * 0.70710678118654752f));
}

// ---------------------------------------------------------------------------
// K2: xw[m][n] += sum over k-chunk of h[m][k]*w2[k][n]  (+ b2[n] on ks==0)
// grid: (ntiles=128, ksplit=4), block 256. kchunk = 256.
__global__ void k2(const float* __restrict__ h, const float* __restrict__ w2,
                   const float* __restrict__ b2, float* __restrict__ xw) {
    const int n  = blockIdx.x * 256 + threadIdx.x;
    const int k0 = blockIdx.y * 256;
    __shared__ float h_lds[BN][256];
    for (int idx = threadIdx.x; idx < BN * 256; idx += 256) {
        int m = idx >> 8, kk = idx & 255;
        h_lds[m][kk] = h[m * INTER + k0 + kk];
    }
    __syncthreads();
    const float init = (blockIdx.y == 0) ? b2[n] : 0.f;
    float acc[BN];
#pragma unroll
    for (int m = 0; m < BN; ++m) acc[m] = init;
    const float* w2p = w2 + (size_t)k0 * NW2 + n;
#pragma unroll 2
    for (int k4 = 0; k4 < 64; ++k4) {
        float wa = w2p[(size_t)(4 * k4 + 0) * NW2];
        float wb = w2p[(size_t)(4 * k4 + 1) * NW2];
        float wc = w2p[(size_t)(4 * k4 + 2) * NW2];
        float wd = w2p[(size_t)(4 * k4 + 3) * NW2];
#pragma unroll
        for (int m = 0; m < BN; ++m) {
            const float4 hv = *reinterpret_cast<const float4*>(&h_lds[m][4 * k4]);
            acc[m] += hv.x * wa + hv.y * wb + hv.z * wc + hv.w * wd;
        }
    }
#pragma unroll
    for (int m = 0; m < BN; ++m) atomicAdd(&xw[m * NW2 + n], acc[m]);
}

// ---------------------------------------------------------------------------
// K3: t[m][r] = sum_c x[m][c] * xw[m][c*8+r]   (x_a half of xw)
// grid: 128 blocks (m*8+r), block 256.
__global__ void k3(const float* __restrict__ x, const float* __restrict__ xw,
                   float* __restrict__ t) {
    const int m = blockIdx.x >> 3, r = blockIdx.x & 7;
    float s = 0.f;
    for (int c = threadIdx.x; c < DN; c += 256)
        s += x[m * DN + c] * xw[m * NW2 + c * 8 + r];
    __shared__ float red[256];
    red[threadIdx.x] = s;
    __syncthreads();
    for (int off = 128; off > 0; off >>= 1) {
        if (threadIdx.x < off) red[threadIdx.x] += red[threadIdx.x + off];
        __syncthreads();
    }
    if (threadIdx.x == 0) t[m * 8 + r] = red[0];
}

// ---------------------------------------------------------------------------
// K4: out[m][o] += sum over c-chunk x[m][c]*base[c][o];
//     ks==0 additionally adds x[m][o] + sum_r t[m][r]*xw[m][HALFN+o*8+r]
// grid: (otiles=8, ksplit=32), block 256. cchunk = 64.
__global__ void k4(const float* __restrict__ x, const float* __restrict__ base,
                   const float* __restrict__ xw, const float* __restrict__ t,
                   float* __restrict__ out) {
    const int o  = blockIdx.x * 256 + threadIdx.x;
    const int c0 = blockIdx.y * 64;
    __shared__ float x_lds[BN][64];
    for (int idx = threadIdx.x; idx < BN * 64; idx += 256) {
        int m = idx >> 6, cc = idx & 63;
        x_lds[m][cc] = x[m * DN + c0 + cc];
    }
    __syncthreads();
    float acc[BN];
#pragma unroll
    for (int m = 0; m < BN; ++m) acc[m] = 0.f;
    const float* bp = base + (size_t)c0 * DN + o;
#pragma unroll 2
    for (int c4 = 0; c4 < 16; ++c4) {
        float ba = bp[(size_t)(4 * c4 + 0) * DN];
        float bb = bp[(size_t)(4 * c4 + 1) * DN];
        float bc = bp[(size_t)(4 * c4 + 2) * DN];
        float bd = bp[(size_t)(4 * c4 + 3) * DN];
#pragma unroll
        for (int m = 0; m < BN; ++m) {
            const float4 xv = *reinterpret_cast<const float4*>(&x_lds[m][4 * c4]);
            acc[m] += xv.x * ba + xv.y * bb + xv.z * bc + xv.w * bd;
        }
    }
    if (blockIdx.y == 0) {
#pragma unroll
        for (int m = 0; m < BN; ++m) {
            const float4 xb0 = *reinterpret_cast<const float4*>(&xw[m * NW2 + HALFN + o * 8]);
            const float4 xb1 = *reinterpret_cast<const float4*>(&xw[m * NW2 + HALFN + o * 8 + 4]);
            float lr = t[m * 8 + 0] * xb0.x + t[m * 8 + 1] * xb0.y +
                       t[m * 8 + 2] * xb0.z + t[m * 8 + 3] * xb0.w +
                       t[m * 8 + 4] * xb1.x + t[m * 8 + 5] * xb1.y +
                       t[m * 8 + 6] * xb1.z + t[m * 8 + 7] * xb1.w;
            acc[m] += lr + x[m * DN + o];
        }
    }
#pragma unroll
    for (int m = 0; m < BN; ++m) atomicAdd(&out[m * DN + o], acc[m]);
}

// ---------------------------------------------------------------------------
extern "C" void kernel_launch(void* const* d_in, const int* in_sizes, int n_in,
                              void* d_out, int out_size, void* d_ws, size_t ws_size,
                              hipStream_t stream) {
    const float* x    = (const float*)d_in[0];
    const float* ada  = (const float*)d_in[1];
    const float* base = (const float*)d_in[2];
    const float* w1   = (const float*)d_in[3];
    const float* b1   = (const float*)d_in[4];
    const float* w2   = (const float*)d_in[5];
    const float* b2   = (const float*)d_in[6];
    float* out = (float*)d_out;

    // ws layout (bytes): xw [0, 2097152) | h_pre [2097152, 2162688)
    //                    | h [2162688, 2228224) | t [2228224, 2228736)
    char* ws = (char*)d_ws;
    float* xw    = (float*)(ws);
    float* h_pre = (float*)(ws + 2097152);
    float* h     = (float*)(ws + 2162688);
    float* t     = (float*)(ws + 2228224);

    // zero the atomic accumulators (xw + h_pre contiguous) and the output
    hipMemsetAsync(d_ws, 0, 2162688, stream);
    hipMemsetAsync(d_out, 0, (size_t)out_size * sizeof(float), stream);

    k1a<<<dim3(4, 32), 256, 0, stream>>>(ada, w1, h_pre);
    k1b<<<64, 256, 0, stream>>>(h_pre, b1, h);
    k2<<<dim3(128, 4), 256, 0, stream>>>(h, w2, b2, xw);
    k3<<<128, 256, 0, stream>>>(x, xw, t);
    k4<<<dim3(8, 32), 256, 0, stream>>>(x, base, xw, t, out);
}

// Round 2
// 73.404 us; speedup vs baseline: 1.3205x; 1.3205x over previous
//
#include <hip/hip_runtime.h>
#include <math.h>

#define BN 16
#define DN 2048
#define ADA 1024
#define INTER 1024
#define NW2 32768   // D*RANK*2
#define HALFN 16384

// ===========================================================================
// K1a: h_pre[m][j] += sum over k-chunk of ada[m][k]*w1[k][j]   (atomic k-split)
// grid: (4, 32), block 256. kchunk = 32.  (small: w1 = 4 MB)
__global__ void k1a(const float* __restrict__ ada, const float* __restrict__ w1,
                    float* __restrict__ h_pre) {
    const int j  = blockIdx.x * 256 + threadIdx.x;
    const int k0 = blockIdx.y * 32;
    __shared__ float a_lds[BN][32];
    for (int idx = threadIdx.x; idx < BN * 32; idx += 256) {
        int m = idx >> 5, kk = idx & 31;
        a_lds[m][kk] = ada[m * ADA + k0 + kk];
    }
    __syncthreads();
    float acc[BN];
#pragma unroll
    for (int m = 0; m < BN; ++m) acc[m] = 0.f;
    for (int kk = 0; kk < 32; ++kk) {
        float w = w1[(k0 + kk) * INTER + j];
#pragma unroll
        for (int m = 0; m < BN; ++m) acc[m] += a_lds[m][kk] * w;
    }
#pragma unroll
    for (int m = 0; m < BN; ++m) atomicAdd(&h_pre[m * INTER + j], acc[m]);
}

// ===========================================================================
// K1b-T: h_t[k][m] = gelu_exact(h_pre[m][k] + b1[k])   (transposed output)
__global__ void k1bt(const float* __restrict__ h_pre, const float* __restrict__ b1,
                     float* __restrict__ h_t) {
    int i = blockIdx.x * 256 + threadIdx.x;     // 16384 elements
    int m = i >> 10, j = i & (INTER - 1);
    float v = h_pre[i] + b1[j];
    float g = 0.5f * v * (1.f + erff(v * 0.70710678118654752f));
    h_t[j * BN + m] = g;
}

// ===========================================================================
// K2m: partial[ks][m][n] = sum_{k in chunk} h_t[k][m] * w2[k][n]
// grid: (64, 8), block 256. Each thread owns a float2 of n; kchunk = 128.
// Per k: 1 global float2 + 4 broadcast ds_read_b128 (all 16 m) + 32 FMA.
#define K2ACC(i, hv) do { acc[i].x = fmaf((hv), w.x, acc[i].x); \
                          acc[i].y = fmaf((hv), w.y, acc[i].y); } while (0)
__global__ __launch_bounds__(256) void k2m(const float* __restrict__ h_t,
                                           const float* __restrict__ w2,
                                           float* __restrict__ p2) {
    const int n2 = blockIdx.x * 256 + threadIdx.x;   // float2 column, [0, 16384)
    const int k0 = blockIdx.y * 128;
    __shared__ float hl[128 * BN];                   // 8 KB, h_t chunk (contiguous)
    {
        const float4* src = (const float4*)(h_t + k0 * BN);
        float4* dst = (float4*)hl;
        dst[threadIdx.x]       = src[threadIdx.x];
        dst[threadIdx.x + 256] = src[threadIdx.x + 256];
    }
    __syncthreads();
    float2 acc[BN];
#pragma unroll
    for (int m = 0; m < BN; ++m) acc[m] = make_float2(0.f, 0.f);
    const float2* wp = (const float2*)w2 + (size_t)k0 * (NW2 / 2) + n2;
#pragma unroll 8
    for (int k = 0; k < 128; ++k) {
        const float2 w = wp[(size_t)k * (NW2 / 2)];
        const float4* hk = (const float4*)(hl + k * BN);
        const float4 h0 = hk[0], h1 = hk[1], h2 = hk[2], h3 = hk[3];
        K2ACC(0,  h0.x); K2ACC(1,  h0.y); K2ACC(2,  h0.z); K2ACC(3,  h0.w);
        K2ACC(4,  h1.x); K2ACC(5,  h1.y); K2ACC(6,  h1.z); K2ACC(7,  h1.w);
        K2ACC(8,  h2.x); K2ACC(9,  h2.y); K2ACC(10, h2.z); K2ACC(11, h2.w);
        K2ACC(12, h3.x); K2ACC(13, h3.y); K2ACC(14, h3.z); K2ACC(15, h3.w);
    }
    float2* op = (float2*)p2 + (size_t)blockIdx.y * (BN * NW2 / 2) + n2;
#pragma unroll
    for (int m = 0; m < BN; ++m) op[(size_t)m * (NW2 / 2)] = acc[m];
}

// ===========================================================================
// K2r: xw[m][n] = b2[n] + sum_ks p2[ks][m][n]    (float4, fully coalesced)
__global__ void k2r(const float* __restrict__ p2, const float* __restrict__ b2,
                    float* __restrict__ xw) {
    const int i  = blockIdx.x * 256 + threadIdx.x;  // float4 idx over 131072
    const int n4 = i & (NW2 / 4 - 1);
    float4 s = ((const float4*)b2)[n4];
    const float4* p = (const float4*)p2 + i;
#pragma unroll
    for (int ks = 0; ks < 8; ++ks) {
        float4 v = p[(size_t)ks * (BN * NW2 / 4)];
        s.x += v.x; s.y += v.y; s.z += v.z; s.w += v.w;
    }
    ((float4*)xw)[i] = s;
}

// ===========================================================================
// K3: t[m][r] = sum_c x[m][c] * xw[m][c*8+r]   (x_a half)
// grid: 128 blocks (m*8+r), block 256.
__global__ void k3(const float* __restrict__ x, const float* __restrict__ xw,
                   float* __restrict__ t) {
    const int m = blockIdx.x >> 3, r = blockIdx.x & 7;
    float s = 0.f;
    for (int c = threadIdx.x; c < DN; c += 256)
        s += x[m * DN + c] * xw[(size_t)m * NW2 + c * 8 + r];
    __shared__ float red[256];
    red[threadIdx.x] = s;
    __syncthreads();
    for (int off = 128; off > 0; off >>= 1) {
        if (threadIdx.x < off) red[threadIdx.x] += red[threadIdx.x + off];
        __syncthreads();
    }
    if (threadIdx.x == 0) t[m * 8 + r] = red[0];
}

// ===========================================================================
// K4m: p4[cs][m][o] = sum_{c in chunk} x[m][c] * base[c][o]
// grid: (4, 64), block 128. Each thread owns a float4 of o; cchunk = 32.
#define K4ACC(i, xv) do { acc[i].x = fmaf((xv), b.x, acc[i].x); \
                          acc[i].y = fmaf((xv), b.y, acc[i].y); \
                          acc[i].z = fmaf((xv), b.z, acc[i].z); \
                          acc[i].w = fmaf((xv), b.w, acc[i].w); } while (0)
__global__ __launch_bounds__(128) void k4m(const float* __restrict__ x,
                                           const float* __restrict__ base,
                                           float* __restrict__ p4) {
    const int o4 = blockIdx.x * 128 + threadIdx.x;   // [0, 512)
    const int c0 = blockIdx.y * 32;
    __shared__ float xt[32 * BN];                    // x chunk transposed [c][m]
    for (int idx = threadIdx.x; idx < 32 * BN; idx += 128) {
        int cc = idx >> 4, m = idx & 15;
        xt[idx] = x[m * DN + c0 + cc];
    }
    __syncthreads();
    float4 acc[BN];
#pragma unroll
    for (int m = 0; m < BN; ++m) acc[m] = make_float4(0.f, 0.f, 0.f, 0.f);
    const float4* bp = (const float4*)base + (size_t)c0 * (DN / 4) + o4;
#pragma unroll 4
    for (int cc = 0; cc < 32; ++cc) {
        const float4 b = bp[(size_t)cc * (DN / 4)];
        const float4* xk = (const float4*)(xt + cc * BN);
        const float4 x0 = xk[0], x1 = xk[1], x2 = xk[2], x3 = xk[3];
        K4ACC(0,  x0.x); K4ACC(1,  x0.y); K4ACC(2,  x0.z); K4ACC(3,  x0.w);
        K4ACC(4,  x1.x); K4ACC(5,  x1.y); K4ACC(6,  x1.z); K4ACC(7,  x1.w);
        K4ACC(8,  x2.x); K4ACC(9,  x2.y); K4ACC(10, x2.z); K4ACC(11, x2.w);
        K4ACC(12, x3.x); K4ACC(13, x3.y); K4ACC(14, x3.z); K4ACC(15, x3.w);
    }
    float4* op = (float4*)p4 + (size_t)blockIdx.y * (BN * DN / 4) + o4;
#pragma unroll
    for (int m = 0; m < BN; ++m) op[m * (DN / 4)] = acc[m];
}

// ===========================================================================
// K5: out[m][o] = x[m][o] + sum_cs p4[cs][m][o] + sum_r t[m][r]*x_b[m][o][r]
__global__ void k5(const float* __restrict__ x, const float* __restrict__ p4,
                   const float* __restrict__ xw, const float* __restrict__ t,
                   float* __restrict__ out) {
    const int i = blockIdx.x * 256 + threadIdx.x;   // [0, 32768)
    const int m = i >> 11, o = i & (DN - 1);
    float s = x[i];
    const float* p = p4 + i;
#pragma unroll 8
    for (int ks = 0; ks < 64; ++ks) s += p[ks * (BN * DN)];
    const float4 xb0 = *(const float4*)(xw + (size_t)m * NW2 + HALFN + o * 8);
    const float4 xb1 = *(const float4*)(xw + (size_t)m * NW2 + HALFN + o * 8 + 4);
    const float* tm = t + m * 8;
    s += tm[0] * xb0.x + tm[1] * xb0.y + tm[2] * xb0.z + tm[3] * xb0.w
       + tm[4] * xb1.x + tm[5] * xb1.y + tm[6] * xb1.z + tm[7] * xb1.w;
    out[i] = s;
}

// ===========================================================================
// ---- Fallback path (round-1 proven kernels), used only if ws too small ----
__global__ void k1b_o(const float* __restrict__ h_pre, const float* __restrict__ b1,
                      float* __restrict__ h) {
    int i = blockIdx.x * 256 + threadIdx.x;
    int j = i & (INTER - 1);
    float v = h_pre[i] + b1[j];
    h[i] = 0.5f * v * (1.f + erff(v * 0.70710678118654752f));
}

__global__ void k2_o(const float* __restrict__ h, const float* __restrict__ w2,
                     const float* __restrict__ b2, float* __restrict__ xw) {
    const int n  = blockIdx.x * 256 + threadIdx.x;
    const int k0 = blockIdx.y * 256;
    __shared__ float h_lds[BN][256];
    for (int idx = threadIdx.x; idx < BN * 256; idx += 256) {
        int m = idx >> 8, kk = idx & 255;
        h_lds[m][kk] = h[m * INTER + k0 + kk];
    }
    __syncthreads();
    const float init = (blockIdx.y == 0) ? b2[n] : 0.f;
    float acc[BN];
#pragma unroll
    for (int m = 0; m < BN; ++m) acc[m] = init;
    const float* w2p = w2 + (size_t)k0 * NW2 + n;
#pragma unroll 2
    for (int k4i = 0; k4i < 64; ++k4i) {
        float wa = w2p[(size_t)(4 * k4i + 0) * NW2];
        float wb = w2p[(size_t)(4 * k4i + 1) * NW2];
        float wc = w2p[(size_t)(4 * k4i + 2) * NW2];
        float wd = w2p[(size_t)(4 * k4i + 3) * NW2];
#pragma unroll
        for (int m = 0; m < BN; ++m) {
            const float4 hv = *reinterpret_cast<const float4*>(&h_lds[m][4 * k4i]);
            acc[m] += hv.x * wa + hv.y * wb + hv.z * wc + hv.w * wd;
        }
    }
#pragma unroll
    for (int m = 0; m < BN; ++m) atomicAdd(&xw[(size_t)m * NW2 + n], acc[m]);
}

__global__ void k4_o(const float* __restrict__ x, const float* __restrict__ base,
                     const float* __restrict__ xw, const float* __restrict__ t,
                     float* __restrict__ out) {
    const int o  = blockIdx.x * 256 + threadIdx.x;
    const int c0 = blockIdx.y * 64;
    __shared__ float x_lds[BN][64];
    for (int idx = threadIdx.x; idx < BN * 64; idx += 256) {
        int m = idx >> 6, cc = idx & 63;
        x_lds[m][cc] = x[m * DN + c0 + cc];
    }
    __syncthreads();
    float acc[BN];
#pragma unroll
    for (int m = 0; m < BN; ++m) acc[m] = 0.f;
    const float* bp = base + (size_t)c0 * DN + o;
#pragma unroll 2
    for (int c4 = 0; c4 < 16; ++c4) {
        float ba = bp[(size_t)(4 * c4 + 0) * DN];
        float bb = bp[(size_t)(4 * c4 + 1) * DN];
        float bc = bp[(size_t)(4 * c4 + 2) * DN];
        float bd = bp[(size_t)(4 * c4 + 3) * DN];
#pragma unroll
        for (int m = 0; m < BN; ++m) {
            const float4 xv = *reinterpret_cast<const float4*>(&x_lds[m][4 * c4]);
            acc[m] += xv.x * ba + xv.y * bb + xv.z * bc + xv.w * bd;
        }
    }
    if (blockIdx.y == 0) {
#pragma unroll
        for (int m = 0; m < BN; ++m) {
            const float4 xb0 = *reinterpret_cast<const float4*>(&xw[(size_t)m * NW2 + HALFN + o * 8]);
            const float4 xb1 = *reinterpret_cast<const float4*>(&xw[(size_t)m * NW2 + HALFN + o * 8 + 4]);
            float lr = t[m * 8 + 0] * xb0.x + t[m * 8 + 1] * xb0.y +
                       t[m * 8 + 2] * xb0.z + t[m * 8 + 3] * xb0.w +
                       t[m * 8 + 4] * xb1.x + t[m * 8 + 5] * xb1.y +
                       t[m * 8 + 6] * xb1.z + t[m * 8 + 7] * xb1.w;
            acc[m] += lr + x[m * DN + o];
        }
    }
#pragma unroll
    for (int m = 0; m < BN; ++m) atomicAdd(&out[m * DN + o], acc[m]);
}

// ===========================================================================
extern "C" void kernel_launch(void* const* d_in, const int* in_sizes, int n_in,
                              void* d_out, int out_size, void* d_ws, size_t ws_size,
                              hipStream_t stream) {
    const float* x    = (const float*)d_in[0];
    const float* ada  = (const float*)d_in[1];
    const float* base = (const float*)d_in[2];
    const float* w1   = (const float*)d_in[3];
    const float* b1   = (const float*)d_in[4];
    const float* w2   = (const float*)d_in[5];
    const float* b2   = (const float*)d_in[6];
    float* out = (float*)d_out;
    char* ws = (char*)d_ws;

    // Main-path ws layout (bytes):
    //   p2    @ 0          (8 * 16*32768*4 = 16,777,216)
    //   xw    @ 16,777,216 (2,097,152)
    //   p4    @ 18,874,368 (64 * 16*2048*4 = 8,388,608)
    //   h_pre @ 27,262,976 (65,536)
    //   h_t   @ 27,328,512 (65,536)
    //   t     @ 27,394,048 (512)
    const size_t NEED = 27394560;

    if (ws_size >= NEED) {
        float* p2    = (float*)(ws);
        float* xw    = (float*)(ws + 16777216);
        float* p4    = (float*)(ws + 18874368);
        float* h_pre = (float*)(ws + 27262976);
        float* h_t   = (float*)(ws + 27328512);
        float* t     = (float*)(ws + 27394048);

        hipMemsetAsync(h_pre, 0, 65536, stream);   // atomic accumulator only
        k1a <<<dim3(4, 32),  256, 0, stream>>>(ada, w1, h_pre);
        k1bt<<<64,           256, 0, stream>>>(h_pre, b1, h_t);
        k2m <<<dim3(64, 8),  256, 0, stream>>>(h_t, w2, p2);
        k4m <<<dim3(4, 64),  128, 0, stream>>>(x, base, p4);
        k2r <<<512,          256, 0, stream>>>(p2, b2, xw);
        k3  <<<128,          256, 0, stream>>>(x, xw, t);
        k5  <<<128,          256, 0, stream>>>(x, p4, xw, t, out);
    } else {
        // round-1 fallback: xw @0, h_pre @2,097,152, h @2,162,688, t @2,228,224
        float* xw    = (float*)(ws);
        float* h_pre = (float*)(ws + 2097152);
        float* h     = (float*)(ws + 2162688);
        float* t     = (float*)(ws + 2228224);
        hipMemsetAsync(ws, 0, 2162688, stream);
        hipMemsetAsync(d_out, 0, (size_t)out_size * sizeof(float), stream);
        k1a <<<dim3(4, 32),  256, 0, stream>>>(ada, w1, h_pre);
        k1b_o<<<64,          256, 0, stream>>>(h_pre, b1, h);
        k2_o<<<dim3(128, 4), 256, 0, stream>>>(h, w2, b2, xw);
        k3  <<<128,          256, 0, stream>>>(x, xw, t);
        k4_o<<<dim3(8, 32),  256, 0, stream>>>(x, base, xw, t, out);
    }
}

// Round 3
// 71.046 us; speedup vs baseline: 1.3643x; 1.0332x over previous
//
#include <hip/hip_runtime.h>
#include <math.h>

#define BN 16
#define DN 2048
#define ADA 1024
#define INTER 1024
#define NW2 32768   // D*RANK*2
#define HALFN 16384

// ===========================================================================
// K1a: h_pre[m][j] += sum over k-chunk of ada[m][k]*w1[k][j]   (atomic k-split)
// grid: (4, 32), block 256. kchunk = 32.  (small: w1 = 4 MB)
__global__ void k1a(const float* __restrict__ ada, const float* __restrict__ w1,
                    float* __restrict__ h_pre) {
    const int j  = blockIdx.x * 256 + threadIdx.x;
    const int k0 = blockIdx.y * 32;
    __shared__ float a_lds[BN][32];
    for (int idx = threadIdx.x; idx < BN * 32; idx += 256) {
        int m = idx >> 5, kk = idx & 31;
        a_lds[m][kk] = ada[m * ADA + k0 + kk];
    }
    __syncthreads();
    float acc[BN];
#pragma unroll
    for (int m = 0; m < BN; ++m) acc[m] = 0.f;
    for (int kk = 0; kk < 32; ++kk) {
        float w = w1[(k0 + kk) * INTER + j];
#pragma unroll
        for (int m = 0; m < BN; ++m) acc[m] += a_lds[m][kk] * w;
    }
#pragma unroll
    for (int m = 0; m < BN; ++m) atomicAdd(&h_pre[m * INTER + j], acc[m]);
}

// ===========================================================================
// K1b-T: h_t[k][m] = gelu_exact(h_pre[m][k] + b1[k])   (transposed output)
__global__ void k1bt(const float* __restrict__ h_pre, const float* __restrict__ b1,
                     float* __restrict__ h_t) {
    int i = blockIdx.x * 256 + threadIdx.x;     // 16384 elements
    int m = i >> 10, j = i & (INTER - 1);
    float v = h_pre[i] + b1[j];
    float g = 0.5f * v * (1.f + erff(v * 0.70710678118654752f));
    h_t[j * BN + m] = g;
}

// ===========================================================================
// K2m: p2[ks][m][n] = sum_{k in 128-chunk} h_t[k][m] * w2[k][n]
// grid: (64, 8), block 256. Thread owns a float2 of n. NO LDS:
//  - h_t read with wave-uniform addresses (64 B/k, contiguous) -> scalar pipe
//  - w2 streamed float2/lane with 8-deep register prefetch (clamped)
#define K2ACC(i, hv) do { acc[i].x = fmaf((hv), w.x, acc[i].x); \
                          acc[i].y = fmaf((hv), w.y, acc[i].y); } while (0)
__global__ __launch_bounds__(256) void k2m(const float* __restrict__ h_t,
                                           const float* __restrict__ w2,
                                           float* __restrict__ p2) {
    const int n2 = blockIdx.x * 256 + threadIdx.x;   // float2 column, [0, 16384)
    const int k0 = blockIdx.y * 128;
    float2 acc[BN];
#pragma unroll
    for (int m = 0; m < BN; ++m) acc[m] = make_float2(0.f, 0.f);

    const float2* wp = (const float2*)w2 + (size_t)k0 * (NW2 / 2) + n2;
    const float4* hp = (const float4*)h_t + (size_t)k0 * 4;   // 4 float4 per k

    float2 wbuf[8];
#pragma unroll
    for (int u = 0; u < 8; ++u) wbuf[u] = wp[(size_t)u * (NW2 / 2)];

    for (int kb = 0; kb < 128; kb += 8) {
#pragma unroll
        for (int u = 0; u < 8; ++u) {
            const int k = kb + u;
            const float2 w = wbuf[u];
            const int kn = (k + 8 < 128) ? (k + 8) : k;       // uniform clamp, no OOB
            wbuf[u] = wp[(size_t)kn * (NW2 / 2)];
            const float4 h0 = hp[k * 4 + 0];
            const float4 h1 = hp[k * 4 + 1];
            const float4 h2 = hp[k * 4 + 2];
            const float4 h3 = hp[k * 4 + 3];
            K2ACC(0,  h0.x); K2ACC(1,  h0.y); K2ACC(2,  h0.z); K2ACC(3,  h0.w);
            K2ACC(4,  h1.x); K2ACC(5,  h1.y); K2ACC(6,  h1.z); K2ACC(7,  h1.w);
            K2ACC(8,  h2.x); K2ACC(9,  h2.y); K2ACC(10, h2.z); K2ACC(11, h2.w);
            K2ACC(12, h3.x); K2ACC(13, h3.y); K2ACC(14, h3.z); K2ACC(15, h3.w);
        }
    }
    float2* op = (float2*)p2 + (size_t)blockIdx.y * (BN * NW2 / 2) + n2;
#pragma unroll
    for (int m = 0; m < BN; ++m) op[(size_t)m * (NW2 / 2)] = acc[m];
}

// ===========================================================================
// K2r: xw[m][n] = b2[n] + sum_{ks<8} p2[ks][m][n]    (float4, fully coalesced)
__global__ void k2r(const float* __restrict__ p2, const float* __restrict__ b2,
                    float* __restrict__ xw) {
    const int i  = blockIdx.x * 256 + threadIdx.x;  // float4 idx over 131072
    const int n4 = i & (NW2 / 4 - 1);
    float4 s = ((const float4*)b2)[n4];
    const float4* p = (const float4*)p2 + i;
#pragma unroll
    for (int ks = 0; ks < 8; ++ks) {
        float4 v = p[(size_t)ks * (BN * NW2 / 4)];
        s.x += v.x; s.y += v.y; s.z += v.z; s.w += v.w;
    }
    ((float4*)xw)[i] = s;
}

// ===========================================================================
// K3: t[m][r] = sum_c x[m][c] * xw[m][c*8+r]   (x_a half)
// grid: 128 blocks (m*8+r), block 256.
__global__ void k3(const float* __restrict__ x, const float* __restrict__ xw,
                   float* __restrict__ t) {
    const int m = blockIdx.x >> 3, r = blockIdx.x & 7;
    float s = 0.f;
    for (int c = threadIdx.x; c < DN; c += 256)
        s += x[m * DN + c] * xw[(size_t)m * NW2 + c * 8 + r];
    __shared__ float red[256];
    red[threadIdx.x] = s;
    __syncthreads();
    for (int off = 128; off > 0; off >>= 1) {
        if (threadIdx.x < off) red[threadIdx.x] += red[threadIdx.x + off];
        __syncthreads();
    }
    if (threadIdx.x == 0) t[m * 8 + r] = red[0];
}

// ===========================================================================
// K4m: p4[cs][m][o] = sum_{c in 32-chunk} x[m][c] * base[c][o]
// grid: (2, 64, 2), block 256. Thread owns a float4 of o for 8 m-values.
// NO LDS: x read wave-uniform (scalar pipe); base 8-deep register prefetch.
#define K4ACC(i, xv) do { acc[i].x = fmaf((xv), b.x, acc[i].x); \
                          acc[i].y = fmaf((xv), b.y, acc[i].y); \
                          acc[i].z = fmaf((xv), b.z, acc[i].z); \
                          acc[i].w = fmaf((xv), b.w, acc[i].w); } while (0)
__global__ __launch_bounds__(256) void k4m(const float* __restrict__ x,
                                           const float* __restrict__ base,
                                           float* __restrict__ p4) {
    const int o4 = blockIdx.x * 256 + threadIdx.x;   // [0, 512)
    const int c0 = blockIdx.y * 32;
    const int m0 = blockIdx.z * 8;
    float4 acc[8];
#pragma unroll
    for (int m = 0; m < 8; ++m) acc[m] = make_float4(0.f, 0.f, 0.f, 0.f);

    const float4* bp = (const float4*)base + (size_t)c0 * (DN / 4) + o4;
    float4 bbuf[8];
#pragma unroll
    for (int u = 0; u < 8; ++u) bbuf[u] = bp[(size_t)u * (DN / 4)];

    for (int cb = 0; cb < 32; cb += 8) {
#pragma unroll
        for (int u = 0; u < 8; ++u) {
            const int cc = cb + u;
            const float4 b = bbuf[u];
            const int cn = (cc + 8 < 32) ? (cc + 8) : cc;    // uniform clamp
            bbuf[u] = bp[(size_t)cn * (DN / 4)];
            const float x0 = x[(m0 + 0) * DN + c0 + cc];
            const float x1 = x[(m0 + 1) * DN + c0 + cc];
            const float x2 = x[(m0 + 2) * DN + c0 + cc];
            const float x3 = x[(m0 + 3) * DN + c0 + cc];
            const float x4 = x[(m0 + 4) * DN + c0 + cc];
            const float x5 = x[(m0 + 5) * DN + c0 + cc];
            const float x6 = x[(m0 + 6) * DN + c0 + cc];
            const float x7 = x[(m0 + 7) * DN + c0 + cc];
            K4ACC(0, x0); K4ACC(1, x1); K4ACC(2, x2); K4ACC(3, x3);
            K4ACC(4, x4); K4ACC(5, x5); K4ACC(6, x6); K4ACC(7, x7);
        }
    }
    float4* op = (float4*)p4 + (size_t)blockIdx.y * (BN * DN / 4)
               + (size_t)m0 * (DN / 4) + o4;
#pragma unroll
    for (int m = 0; m < 8; ++m) op[(size_t)m * (DN / 4)] = acc[m];
}

// ===========================================================================
// K5: out[m][o] = x[m][o] + sum_{cs<64} p4[cs][m][o] + sum_r t[m][r]*x_b[m][o][r]
__global__ void k5(const float* __restrict__ x, const float* __restrict__ p4,
                   const float* __restrict__ xw, const float* __restrict__ t,
                   float* __restrict__ out) {
    const int i = blockIdx.x * 256 + threadIdx.x;   // [0, 32768)
    const int m = i >> 11, o = i & (DN - 1);
    float s = x[i];
    const float* p = p4 + i;
#pragma unroll 8
    for (int ks = 0; ks < 64; ++ks) s += p[ks * (BN * DN)];
    const float4 xb0 = *(const float4*)(xw + (size_t)m * NW2 + HALFN + o * 8);
    const float4 xb1 = *(const float4*)(xw + (size_t)m * NW2 + HALFN + o * 8 + 4);
    const float* tm = t + m * 8;
    s += tm[0] * xb0.x + tm[1] * xb0.y + tm[2] * xb0.z + tm[3] * xb0.w
       + tm[4] * xb1.x + tm[5] * xb1.y + tm[6] * xb1.z + tm[7] * xb1.w;
    out[i] = s;
}

// ===========================================================================
extern "C" void kernel_launch(void* const* d_in, const int* in_sizes, int n_in,
                              void* d_out, int out_size, void* d_ws, size_t ws_size,
                              hipStream_t stream) {
    const float* x    = (const float*)d_in[0];
    const float* ada  = (const float*)d_in[1];
    const float* base = (const float*)d_in[2];
    const float* w1   = (const float*)d_in[3];
    const float* b1   = (const float*)d_in[4];
    const float* w2   = (const float*)d_in[5];
    const float* b2   = (const float*)d_in[6];
    float* out = (float*)d_out;
    char* ws = (char*)d_ws;

    // ws layout (bytes):
    //   p2    @ 0           (8 * 16*32768*4 = 16,777,216)
    //   xw    @ 16,777,216  (2,097,152)
    //   p4    @ 18,874,368  (64 * 16*2048*4 = 8,388,608)
    //   h_pre @ 27,262,976  (65,536)
    //   h_t   @ 27,328,512  (65,536)
    //   t     @ 27,394,048  (512)
    // total 27,394,560 bytes — verified available (round-2 main path ran).
    float* p2    = (float*)(ws);
    float* xw    = (float*)(ws + 16777216);
    float* p4    = (float*)(ws + 18874368);
    float* h_pre = (float*)(ws + 27262976);
    float* h_t   = (float*)(ws + 27328512);
    float* t     = (float*)(ws + 27394048);

    hipMemsetAsync(h_pre, 0, 65536, stream);   // k1a atomic accumulator only

    k1a <<<dim3(4, 32),    256, 0, stream>>>(ada, w1, h_pre);
    k1bt<<<64,             256, 0, stream>>>(h_pre, b1, h_t);
    k2m <<<dim3(64, 8),    256, 0, stream>>>(h_t, w2, p2);
    k4m <<<dim3(2, 64, 2), 256, 0, stream>>>(x, base, p4);
    k2r <<<512,            256, 0, stream>>>(p2, b2, xw);
    k3  <<<128,            256, 0, stream>>>(x, xw, t);
    k5  <<<128,            256, 0, stream>>>(x, p4, xw, t, out);
}